// Round 6
// baseline (110.976 us; speedup 1.0000x reference)
//
#include <hip/hip_runtime.h>
#include <hip/hip_bf16.h>

// Problem constants
#define OUT_H 14
#define OUT_W 14
#define C_CH  256
#define SRC_H 200
#define SRC_W 304
#define M_ROI 1024
#define PLANE   (SRC_H * SRC_W)       // 60800
#define OUT_HW  (OUT_H * OUT_W)       // 196

// One block = (1 channel, ROIS_PB rois). Grid ordered so each XCD works
// through its 32 channels sequentially; concurrent blocks per XCD span
// ~1.5 channel-sets (4 img x 243KB) -> L2-resident cross-roi line reuse.
#define ROIS_PB 8
#define CHUNKS  (M_ROI / ROIS_PB)     // 128
#define NXCD    8
#define CH_PER_XCD (C_CH / NXCD)      // 32
#define ELEMS   (ROIS_PB * OUT_HW)    // 1568
#define BLK     320                   // 5 waves: 1568/320 = 4.9 -> 2% tail waste
#define NITER   ((ELEMS + BLK - 1) / BLK)  // 5

typedef float f2 __attribute__((ext_vector_type(2), aligned(4)));

__global__ __launch_bounds__(BLK) void roi_crop_kernel(
    const float* __restrict__ src,
    const float* __restrict__ rois,
    float* __restrict__ out)
{
    const int bid = blockIdx.x;
    // XCD-aware decode: hardware round-robins bid % 8 across XCDs.
    // XCD x receives j = bid>>3 in order; channel changes every 128 blocks.
    const int x     = bid & (NXCD - 1);
    const int j     = bid >> 3;              // 0..4095 per XCD
    const int c     = x * CH_PER_XCD + (j >> 7);
    const int chunk = j & 127;               // j % CHUNKS-per-channel
    const int roi0  = chunk * ROIS_PB;
    const int t     = threadIdx.x;

    // Per-roi separable tables; clamp folded into (base, weight):
    //  row: base=min(y0,198)*304, wy += (y0==199)  -> taps rows r,r+1 valid
    //  col: base=min(x0,302),     wx += (x0==303)  -> taps cols c,c+1 valid
    __shared__ int   s_row[ROIS_PB * OUT_H];
    __shared__ float s_wy [ROIS_PB * OUT_H];
    __shared__ int   s_col[ROIS_PB * OUT_W];
    __shared__ float s_wx [ROIS_PB * OUT_W];
    __shared__ int   s_pbase[ROIS_PB];       // (b*256 + c) * PLANE
    __shared__ int   s_obase[ROIS_PB];       // (roi0+r)*256*196 + c*196

    if (t < ROIS_PB * (OUT_H + OUT_W)) {     // 224 threads
        const int r = t / (OUT_H + OUT_W);
        const int e = t - r * (OUT_H + OUT_W);
        const int rm = roi0 + r;

        float bf = rois[rm * 5 + 0];
        float x1 = rois[rm * 5 + 1];
        float y1 = rois[rm * 5 + 2];
        float x2 = rois[rm * 5 + 3];
        float y2 = rois[rm * 5 + 4];

        // KEEP_AR, _AR = 1.0
        float h  = y2 - y1 + 1.0f;
        float w  = x2 - x1 + 1.0f;
        float ew = (h - w) * 0.5f;
        float eh = (w - h) * 0.5f;
        if (ew > 0.0f) { x1 -= ew; x2 += ew; }
        else           { y1 -= eh; y2 += eh; }

        // EXTEND_RATIO = 0.1 -> each side + size*0.05
        float sw = x2 - x1 + 1.0f;
        float sh = y2 - y1 + 1.0f;
        x1 -= sw * 0.05f; x2 += sw * 0.05f;
        y1 -= sh * 0.05f; y2 += sh * 0.05f;

        if (e < OUT_H) {
            float ty = (float)e * (1.0f / (OUT_H - 1));
            float ys = y1 + (y2 - y1) * ty;
            ys = fminf(fmaxf(ys, 0.0f), (float)(SRC_H - 1));
            float y0f = floorf(ys);
            int   y0  = (int)y0f;
            s_row[r * OUT_H + e] = min(y0, SRC_H - 2) * SRC_W;
            s_wy [r * OUT_H + e] = (ys - y0f) + (y0 > SRC_H - 2 ? 1.0f : 0.0f);
            if (e == 0) {
                s_pbase[r] = ((int)bf * C_CH + c) * PLANE;
                s_obase[r] = rm * (C_CH * OUT_HW) + c * OUT_HW;
            }
        } else {
            int i = e - OUT_H;
            float tx = (float)i * (1.0f / (OUT_W - 1));
            float xs = x1 + (x2 - x1) * tx;
            xs = fminf(fmaxf(xs, 0.0f), (float)(SRC_W - 1));
            float x0f = floorf(xs);
            int   x0  = (int)x0f;
            s_col[r * OUT_W + i] = min(x0, SRC_W - 2);
            s_wx [r * OUT_W + i] = (xs - x0f) + (x0 > SRC_W - 2 ? 1.0f : 0.0f);
        }
    }
    __syncthreads();

#pragma unroll
    for (int k = 0; k < NITER; ++k) {
        int idx = t + k * BLK;
        if (idx < ELEMS) {
            unsigned u  = (unsigned)idx;
            unsigned r  = u / 196u;            // roi-local (magic-mul)
            unsigned p  = u - r * 196u;
            unsigned oy = p / 14u;
            unsigned ox = p - oy * 14u;

            const float* ptr = src + s_pbase[r]
                             + s_row[r * OUT_H + oy] + s_col[r * OUT_W + ox];
            float wx = s_wx[r * OUT_W + ox];
            float wy = s_wy[r * OUT_H + oy];

            f2 top = *(const f2*)ptr;            // (r0,c0),(r0,c0+1)
            f2 bot = *(const f2*)(ptr + SRC_W);  // (r1,c0),(r1,c0+1)

            float tv = top.x + (top.y - top.x) * wx;
            float bv = bot.x + (bot.y - bot.x) * wx;

            __builtin_nontemporal_store(tv + (bv - tv) * wy,
                                        out + s_obase[r] + (int)p);
        }
    }
}

extern "C" void kernel_launch(void* const* d_in, const int* in_sizes, int n_in,
                              void* d_out, int out_size, void* d_ws, size_t ws_size,
                              hipStream_t stream)
{
    const float* src  = (const float*)d_in[0];
    const float* rois = (const float*)d_in[1];
    float* out = (float*)d_out;

    dim3 grid(C_CH * CHUNKS);   // 32768 blocks = 8 XCD x 32 ch x 128 chunks
    dim3 block(BLK);
    roi_crop_kernel<<<grid, block, 0, stream>>>(src, rois, out);
}